// Round 1
// baseline (1819.251 us; speedup 1.0000x reference)
//
#include <hip/hip_runtime.h>
#include <math.h>

#define EPS 1e-5f

// Shapes: B=4, Cin=512, Ci=128, Cq=16, Cout=19, H=W=64, N=4096
// gamma_sa / gamma_sc are 0 in the benchmark inputs -> attention branches are
// runtime-dead. They are implemented (guarded, slow-path) for general
// correctness; all guard branches are device-side so graph capture is safe.

// ---------------- bn coefficient prep: coef[0:128]=scale, coef[128:256]=shift ----
__global__ void bn_prep(const float* __restrict__ s, const float* __restrict__ b,
                        const float* __restrict__ m, const float* __restrict__ v,
                        float* __restrict__ coef) {
    int i = threadIdx.x;
    if (i < 128) {
        float inv = s[i] / sqrtf(v[i] + EPS);
        coef[i] = inv;
        coef[128 + i] = b[i] - m[i] * inv;
    }
}

// ---------------- weight transpose: w[O=128][C][3][3] -> wT[C][9][128] ----------
__global__ void wtrans(const float* __restrict__ w, float* __restrict__ wT, int CIN) {
    int i = blockIdx.x * 256 + threadIdx.x;
    int total = 128 * CIN * 9;
    if (i >= total) return;
    int o   = i / (CIN * 9);
    int rem = i - o * (CIN * 9);
    int c   = rem / 9;
    int tap = rem - c * 9;
    wT[((size_t)c * 9 + tap) * 128 + o] = w[i];
}

// ---------------- fused 3x3 conv + BN + ReLU (+optional accumulate into out) ----
// in: [B, CIN, 64, 64], wT: [CIN][9][128], out: [B,128,64,64]
// Block: 256 threads. Tile: 32x8 spatial, 32 output channels.
// Thread: 4 oc x 8 px accumulators.
// If sel != nullptr and sel[0] != 0, reads inB instead of inA (attention path).
template <int CIN, bool ACCUM>
__launch_bounds__(256)
__global__ void conv3x3_bnrelu(const float* __restrict__ inA,
                               const float* __restrict__ inB,
                               const float* __restrict__ sel,
                               const float* __restrict__ wT,
                               const float* __restrict__ coef,
                               float* __restrict__ out) {
    const float* in = inA;
    if (sel != nullptr && sel[0] != 0.0f) in = inB;

    const int tileid = blockIdx.x;      // 0..15
    const int ocb    = blockIdx.y;      // 0..3
    const int b      = blockIdx.z;      // 0..3
    const int bx0 = (tileid & 1) * 32;
    const int by0 = (tileid >> 1) * 8;

    const int tid = threadIdx.x;
    const int toc = tid >> 5;           // 0..7 (oc group of 4)
    const int ty  = (tid >> 2) & 7;     // 0..7 (row)
    const int tx  = tid & 3;            // 0..3 (8-px column segment)
    const int x0  = bx0 + tx * 8;

    __shared__ float s_in[8][10][34];
    __shared__ float s_w[8][9][32];

    float acc[4][8];
#pragma unroll
    for (int o = 0; o < 4; o++)
#pragma unroll
        for (int p = 0; p < 8; p++) acc[o][p] = 0.0f;

    for (int cc = 0; cc < CIN; cc += 8) {
        // stage input halo tile: 8 channels x 10 rows x 34 cols
        for (int i = tid; i < 8 * 10 * 34; i += 256) {
            int c   = i / 340;
            int r   = (i - c * 340) / 34;
            int col = i - c * 340 - r * 34;
            int gy = by0 + r - 1;
            int gx = bx0 + col - 1;
            float val = 0.0f;
            if ((unsigned)gy < 64u && (unsigned)gx < 64u)
                val = in[(((size_t)b * CIN + cc + c) * 64 + gy) * 64 + gx];
            s_in[c][r][col] = val;
        }
        // stage weights: 8 channels x 9 taps x 32 ocs
        for (int i = tid; i < 8 * 9 * 32; i += 256) {
            int c   = i / 288;
            int rem = i - c * 288;
            int tap = rem >> 5;
            int o   = rem & 31;
            s_w[c][tap][o] = wT[((size_t)(cc + c) * 9 + tap) * 128 + ocb * 32 + o];
        }
        __syncthreads();

#pragma unroll
        for (int c = 0; c < 8; c++) {
#pragma unroll
            for (int ky = 0; ky < 3; ky++) {
                float rowv[10];
#pragma unroll
                for (int j = 0; j < 10; j++) rowv[j] = s_in[c][ty + ky][tx * 8 + j];
#pragma unroll
                for (int kx = 0; kx < 3; kx++) {
                    float w0 = s_w[c][ky * 3 + kx][toc * 4 + 0];
                    float w1 = s_w[c][ky * 3 + kx][toc * 4 + 1];
                    float w2 = s_w[c][ky * 3 + kx][toc * 4 + 2];
                    float w3 = s_w[c][ky * 3 + kx][toc * 4 + 3];
#pragma unroll
                    for (int p = 0; p < 8; p++) {
                        float iv = rowv[p + kx];
                        acc[0][p] += w0 * iv;
                        acc[1][p] += w1 * iv;
                        acc[2][p] += w2 * iv;
                        acc[3][p] += w3 * iv;
                    }
                }
            }
        }
        __syncthreads();
    }

    // epilogue: BN + ReLU (+accumulate)
#pragma unroll
    for (int o = 0; o < 4; o++) {
        int oc = ocb * 32 + toc * 4 + o;
        float sc = coef[oc];
        float sh = coef[128 + oc];
        size_t base = (((size_t)b * 128 + oc) * 64 + (by0 + ty)) * 64 + x0;
#pragma unroll
        for (int p = 0; p < 8; p++) {
            float v = acc[o][p] * sc + sh;
            v = v > 0.0f ? v : 0.0f;
            if (ACCUM) v += out[base + p];
            out[base + p] = v;
        }
    }
}

// ---------------- final 1x1 conv: fsum [B,128,4096] -> out [B,19,4096] ----------
__launch_bounds__(256)
__global__ void conv1x1_out(const float* __restrict__ fsum,
                            const float* __restrict__ w8,   // [19][128]
                            const float* __restrict__ b8,   // [19]
                            float* __restrict__ out) {
    __shared__ float s_w[128][20];  // transposed, padded
    const int tid = threadIdx.x;
    const int b   = blockIdx.y;
    const int px  = blockIdx.x * 256 + tid;
    for (int i = tid; i < 19 * 128; i += 256) {
        int o = i / 128;
        int c = i - o * 128;
        s_w[c][o] = w8[i];
    }
    __syncthreads();
    float acc[19];
#pragma unroll
    for (int o = 0; o < 19; o++) acc[o] = 0.0f;
    for (int c = 0; c < 128; c++) {
        float iv = fsum[((size_t)b * 128 + c) * 4096 + px];
#pragma unroll
        for (int o = 0; o < 19; o++) acc[o] += iv * s_w[c][o];
    }
#pragma unroll
    for (int o = 0; o < 19; o++)
        out[((size_t)b * 19 + o) * 4096 + px] = acc[o] + b8[o];
}

// ================= guarded fallback path (gamma != 0; never runs in bench) =====

// generic 1x1 projection: feat [B,128,4096] -> outp [B,OC,4096], w [OC][128]
template <int OC>
__global__ void lin1x1(const float* __restrict__ gamma, const float* __restrict__ feat,
                       const float* __restrict__ w, const float* __restrict__ bias,
                       float* __restrict__ outp) {
    if (gamma[0] == 0.0f) return;
    __shared__ float s_w[64 * 128];
    const int tid = threadIdx.x;
    const int b   = blockIdx.y;
    const int px  = blockIdx.x * 256 + tid;
    for (int wc = 0; wc < OC; wc += 64) {
        int rows = (OC - wc) < 64 ? (OC - wc) : 64;
        for (int i = tid; i < rows * 128; i += 256) s_w[i] = w[wc * 128 + i];
        __syncthreads();
        for (int ob = 0; ob < rows; ob += 16) {
            float acc[16];
#pragma unroll
            for (int o = 0; o < 16; o++) acc[o] = 0.0f;
            for (int c = 0; c < 128; c++) {
                float iv = feat[((size_t)b * 128 + c) * 4096 + px];
#pragma unroll
                for (int o = 0; o < 16; o++) acc[o] += iv * s_w[(ob + o) * 128 + c];
            }
#pragma unroll
            for (int o = 0; o < 16; o++)
                outp[((size_t)b * OC + wc + ob + o) * 4096 + px] =
                    acc[o] + bias[wc + ob + o];
        }
        __syncthreads();
    }
}

// spatial attention (flash-row style): per block one (b, n) query row.
// q [B,16,4096], v [B,128,4096]; writes b2 = feat1 + gamma * out
__global__ void sa_attn(const float* __restrict__ gamma, const float* __restrict__ q,
                        const float* __restrict__ v, const float* __restrict__ feat1,
                        float* __restrict__ b2) {
    if (gamma[0] == 0.0f) return;
    const int n = blockIdx.x;
    const int b = blockIdx.y;
    const int tid = threadIdx.x;  // 128 threads
    __shared__ float s_q[16];
    __shared__ float s_e[4096];
    __shared__ float s_red[128];
    if (tid < 16) s_q[tid] = q[((size_t)b * 16 + tid) * 4096 + n];
    __syncthreads();
    float lmax = -1e30f;
    for (int m = tid; m < 4096; m += 128) {
        float e = 0.0f;
#pragma unroll
        for (int k = 0; k < 16; k++) e += s_q[k] * q[((size_t)b * 16 + k) * 4096 + m];
        s_e[m] = e;
        lmax = fmaxf(lmax, e);
    }
    s_red[tid] = lmax;
    __syncthreads();
    for (int s = 64; s > 0; s >>= 1) {
        if (tid < s) s_red[tid] = fmaxf(s_red[tid], s_red[tid + s]);
        __syncthreads();
    }
    float mx = s_red[0];
    __syncthreads();
    float lsum = 0.0f;
    for (int m = tid; m < 4096; m += 128) {
        float p = expf(s_e[m] - mx);
        s_e[m] = p;
        lsum += p;
    }
    s_red[tid] = lsum;
    __syncthreads();
    for (int s = 64; s > 0; s >>= 1) {
        if (tid < s) s_red[tid] += s_red[tid + s];
        __syncthreads();
    }
    float inv = 1.0f / s_red[0];
    __syncthreads();
    // thread tid = output channel
    float acc = 0.0f;
    for (int m = 0; m < 4096; m++) acc += s_e[m] * v[((size_t)b * 128 + tid) * 4096 + m];
    size_t idx = ((size_t)b * 128 + tid) * 4096 + n;
    b2[idx] = feat1[idx] + gamma[0] * acc * inv;
}

// channel attention: per block one (b, c) row. writes b2 = feat2 + gamma*out
__global__ void ca_attn(const float* __restrict__ gamma, const float* __restrict__ feat2,
                        float* __restrict__ b2) {
    if (gamma[0] == 0.0f) return;
    const int c = blockIdx.x;
    const int b = blockIdx.y;
    const int tid = threadIdx.x;  // 128 threads
    __shared__ float s_a[128];
    __shared__ float s_red[128];
    const float* xc = feat2 + ((size_t)b * 128 + c) * 4096;
    const float* xd = feat2 + ((size_t)b * 128 + tid) * 4096;
    float e = 0.0f;
    for (int n = 0; n < 4096; n++) e += xc[n] * xd[n];
    // mx = max_d e
    s_red[tid] = e;
    __syncthreads();
    for (int s = 64; s > 0; s >>= 1) {
        if (tid < s) s_red[tid] = fmaxf(s_red[tid], s_red[tid + s]);
        __syncthreads();
    }
    float mx = s_red[0];
    __syncthreads();
    float en = mx - e;
    // m2 = max_d en
    s_red[tid] = en;
    __syncthreads();
    for (int s = 64; s > 0; s >>= 1) {
        if (tid < s) s_red[tid] = fmaxf(s_red[tid], s_red[tid + s]);
        __syncthreads();
    }
    float m2 = s_red[0];
    __syncthreads();
    float p = expf(en - m2);
    s_red[tid] = p;
    __syncthreads();
    for (int s = 64; s > 0; s >>= 1) {
        if (tid < s) s_red[tid] += s_red[tid + s];
        __syncthreads();
    }
    float attn = p / s_red[0];
    s_a[tid] = attn;
    __syncthreads();
    for (int n = tid; n < 4096; n += 128) {
        float acc = 0.0f;
#pragma unroll 8
        for (int d = 0; d < 128; d++)
            acc += s_a[d] * feat2[((size_t)b * 128 + d) * 4096 + n];
        size_t idx = ((size_t)b * 128 + c) * 4096 + n;
        b2[idx] = feat2[idx] + gamma[0] * acc;
    }
}

// ================================ launch =======================================
extern "C" void kernel_launch(void* const* d_in, const int* in_sizes, int n_in,
                              void* d_out, int out_size, void* d_ws, size_t ws_size,
                              hipStream_t stream) {
    const float* x      = (const float*)d_in[0];
    const float* w5a    = (const float*)d_in[1];
    const float* bn5a_s = (const float*)d_in[2];
    const float* bn5a_b = (const float*)d_in[3];
    const float* bn5a_m = (const float*)d_in[4];
    const float* bn5a_v = (const float*)d_in[5];
    const float* w5c    = (const float*)d_in[6];
    const float* bn5c_s = (const float*)d_in[7];
    const float* bn5c_b = (const float*)d_in[8];
    const float* bn5c_m = (const float*)d_in[9];
    const float* bn5c_v = (const float*)d_in[10];
    const float* q_w    = (const float*)d_in[11];
    const float* q_b    = (const float*)d_in[12];
    const float* v_w    = (const float*)d_in[13];
    const float* v_b    = (const float*)d_in[14];
    const float* g_sa   = (const float*)d_in[15];
    const float* g_sc   = (const float*)d_in[16];
    const float* w51    = (const float*)d_in[17];
    const float* bn51_s = (const float*)d_in[18];
    const float* bn51_b = (const float*)d_in[19];
    const float* bn51_m = (const float*)d_in[20];
    const float* bn51_v = (const float*)d_in[21];
    const float* w52    = (const float*)d_in[22];
    const float* bn52_s = (const float*)d_in[23];
    const float* bn52_b = (const float*)d_in[24];
    const float* bn52_m = (const float*)d_in[25];
    const float* bn52_v = (const float*)d_in[26];
    const float* w8     = (const float*)d_in[27];
    const float* b8     = (const float*)d_in[28];
    float* out = (float*)d_out;

    // workspace layout (floats); total ~48.9 MB
    float* ws   = (float*)d_ws;
    float* b0   = ws;                  // feat1  [4,128,64,64]
    float* b1   = b0 + 2097152;        // feat2
    float* b2   = b1 + 2097152;        // sa_feat / sc_feat (fallback only)
    float* b3   = b2 + 2097152;        // sa_conv (+= sc_conv)
    float* wT5a = b3 + 2097152;        // [512][9][128]
    float* wT5c = wT5a + 589824;
    float* wT51 = wT5c + 589824;       // [128][9][128]
    float* wT52 = wT51 + 147456;
    float* c5a  = wT52 + 147456;       // bn coeffs, 256 each
    float* c5c  = c5a + 256;
    float* c51  = c5c + 256;
    float* c52  = c51 + 256;
    float* qbuf = c52 + 256;           // [4,16,4096]
    float* vbuf = qbuf + 262144;       // [4,128,4096]
    (void)ws_size; (void)in_sizes; (void)n_in; (void)out_size;

    // prep: bn coeffs + transposed weights
    bn_prep<<<1, 128, 0, stream>>>(bn5a_s, bn5a_b, bn5a_m, bn5a_v, c5a);
    bn_prep<<<1, 128, 0, stream>>>(bn5c_s, bn5c_b, bn5c_m, bn5c_v, c5c);
    bn_prep<<<1, 128, 0, stream>>>(bn51_s, bn51_b, bn51_m, bn51_v, c51);
    bn_prep<<<1, 128, 0, stream>>>(bn52_s, bn52_b, bn52_m, bn52_v, c52);
    wtrans<<<(128 * 512 * 9 + 255) / 256, 256, 0, stream>>>(w5a, wT5a, 512);
    wtrans<<<(128 * 512 * 9 + 255) / 256, 256, 0, stream>>>(w5c, wT5c, 512);
    wtrans<<<(128 * 128 * 9 + 255) / 256, 256, 0, stream>>>(w51, wT51, 128);
    wtrans<<<(128 * 128 * 9 + 255) / 256, 256, 0, stream>>>(w52, wT52, 128);

    dim3 cgrid(16, 4, 4);
    // feat1 = CBR(x, 5a); feat2 = CBR(x, 5c)
    conv3x3_bnrelu<512, false><<<cgrid, 256, 0, stream>>>(x, nullptr, nullptr, wT5a, c5a, b0);
    conv3x3_bnrelu<512, false><<<cgrid, 256, 0, stream>>>(x, nullptr, nullptr, wT5c, c5c, b1);

    // spatial attention (device-guarded; no-op when gamma_sa == 0)
    lin1x1<16><<<dim3(16, 4), 256, 0, stream>>>(g_sa, b0, q_w, q_b, qbuf);
    lin1x1<128><<<dim3(16, 4), 256, 0, stream>>>(g_sa, b0, v_w, v_b, vbuf);
    sa_attn<<<dim3(4096, 4), 128, 0, stream>>>(g_sa, qbuf, vbuf, b0, b2);

    // sa_conv = CBR(sa_feat, 51): reads b2 iff gamma_sa != 0, else b0
    conv3x3_bnrelu<128, false><<<cgrid, 256, 0, stream>>>(b0, b2, g_sa, wT51, c51, b3);

    // channel attention (device-guarded)
    ca_attn<<<dim3(128, 4), 128, 0, stream>>>(g_sc, b1, b2);

    // b3 += CBR(sc_feat, 52): reads b2 iff gamma_sc != 0, else b1
    conv3x3_bnrelu<128, true><<<cgrid, 256, 0, stream>>>(b1, b2, g_sc, wT52, c52, b3);

    // out = 1x1 conv + bias
    conv1x1_out<<<dim3(16, 4), 256, 0, stream>>>(b3, w8, b8, out);
}

// Round 2
// 413.316 us; speedup vs baseline: 4.4016x; 4.4016x over previous
//
#include <hip/hip_runtime.h>
#include <math.h>

#define EPS 1e-5f

// ---------------------------------------------------------------------------
// SegHead on MI355X via split-precision bf16 MFMA implicit-GEMM convs.
// gamma_sa/gamma_sc == 0 in bench inputs -> attention guarded device-side.
// fp32 value v is split v = hi + lo (both bf16); A*B uses 3 MFMA terms
// (hh, hl, lh), dropping lo*lo (~2^-18 relative) -> fp32-grade accuracy.
// ---------------------------------------------------------------------------

typedef unsigned int uint;
typedef unsigned short u16;
typedef u16 u16x4 __attribute__((ext_vector_type(4)));
typedef u16 u16x8 __attribute__((ext_vector_type(8)));
typedef __bf16 bf16x8 __attribute__((ext_vector_type(8)));
typedef float f32x4 __attribute__((ext_vector_type(4)));
typedef float f32x16 __attribute__((ext_vector_type(16)));

__device__ __forceinline__ u16 f2bf(float f) {
    uint u = __float_as_uint(f);
    u = u + 0x7FFF + ((u >> 16) & 1);   // RNE
    return (u16)(u >> 16);
}
__device__ __forceinline__ float bf2f(u16 h) {
    return __uint_as_float(((uint)h) << 16);
}

__device__ __forceinline__ void gl_lds16(const void* g, void* l) {
    __builtin_amdgcn_global_load_lds(
        (const __attribute__((address_space(1))) unsigned int*)g,
        (__attribute__((address_space(3))) unsigned int*)l, 16, 0, 0);
}

// ---------------- bn coefficients for all 4 convs in one launch ---------------
__global__ void bn_prep_all(const float* s0, const float* b0, const float* m0, const float* v0,
                            const float* s1, const float* b1, const float* m1, const float* v1,
                            const float* s2, const float* b2, const float* m2, const float* v2,
                            const float* s3, const float* b3, const float* m3, const float* v3,
                            float* c0, float* c1, float* c2, float* c3) {
    int k = blockIdx.x, i = threadIdx.x;
    const float *s, *bb, *mm, *vv; float* cf;
    if (k == 0)      { s = s0; bb = b0; mm = m0; vv = v0; cf = c0; }
    else if (k == 1) { s = s1; bb = b1; mm = m1; vv = v1; cf = c1; }
    else if (k == 2) { s = s2; bb = b2; mm = m2; vv = v2; cf = c2; }
    else             { s = s3; bb = b3; mm = m3; vv = v3; cf = c3; }
    float inv = s[i] / sqrtf(vv[i] + EPS);
    cf[i] = inv;
    cf[128 + i] = bb[i] - mm[i] * inv;
}

// ---------------- zero the 1-px borders of the padded NHWC bf16 buffers ------
__global__ void border_zero(u16* x0h, u16* x0l, u16* x1h, u16* x1l, u16* x2h, u16* x2l) {
    int p = blockIdx.x;            // 0..1039 (260 border px * 4 images)
    int img = p / 260, pe = p % 260;
    int y, x;
    if (pe < 66)       { y = 0;  x = pe; }
    else if (pe < 132) { y = 65; x = pe - 66; }
    else { int q = pe - 132; y = 1 + (q >> 1); x = (q & 1) * 65; }
    int buf = blockIdx.y, tid = threadIdx.x;
    if (buf == 0) {
        size_t base = (((size_t)img * 66 + y) * 66 + x) * 512;
        for (int c = tid; c < 512; c += 256) { x0h[base + c] = 0; x0l[base + c] = 0; }
    } else {
        u16* hh = (buf == 1) ? x1h : x2h;
        u16* ll = (buf == 1) ? x1l : x2l;
        size_t base = (((size_t)img * 66 + y) * 66 + x) * 128;
        for (int c = tid; c < 128; c += 256) { hh[base + c] = 0; ll[base + c] = 0; }
    }
}

// ---------------- weights: [O=128][CIN][3][3] fp32 -> [tap][oc][ic] hi/lo ----
template <int CIN>
__global__ void pack_w(const float* __restrict__ w0, u16* __restrict__ h0, u16* __restrict__ l0,
                       const float* __restrict__ w1, u16* __restrict__ h1, u16* __restrict__ l1) {
    const float* w = blockIdx.z ? w1 : w0;
    u16* hh = blockIdx.z ? h1 : h0;
    u16* ll = blockIdx.z ? l1 : l0;
    int i = blockIdx.x * 256 + threadIdx.x;      // == dst index (tap*128+oc)*CIN+ic
    int ic = i & (CIN - 1);
    int rest = i / CIN;
    int oc = rest & 127;
    int tap = rest >> 7;
    float f = w[((size_t)oc * CIN + ic) * 9 + tap];
    u16 h = f2bf(f);
    hh[i] = h;
    ll[i] = f2bf(f - bf2f(h));
}

// ---------------- x: [4][512][64][64] fp32 NCHW -> padded NHWC hi/lo bf16 ----
__global__ void pack_x(const float* __restrict__ x, u16* __restrict__ xh, u16* __restrict__ xl) {
    __shared__ float tile[64][68];
    int cb = blockIdx.x, y = blockIdx.y, b = blockIdx.z, tid = threadIdx.x;
    int cl = tid >> 2, seg = tid & 3;
    const float* src = x + (((size_t)b * 512 + cb * 64 + cl) * 64 + y) * 64 + seg * 16;
#pragma unroll
    for (int j = 0; j < 4; j++)
        *(f32x4*)&tile[cl][seg * 16 + j * 4] = *(const f32x4*)(src + j * 4);
    __syncthreads();
    int pxl = tid >> 2, cg = tid & 3;
    u16x8 h0, h1, l0, l1;
#pragma unroll
    for (int j = 0; j < 8; j++) {
        float v = tile[cg * 16 + j][pxl];
        u16 h = f2bf(v); h0[j] = h; l0[j] = f2bf(v - bf2f(h));
    }
#pragma unroll
    for (int j = 0; j < 8; j++) {
        float v = tile[cg * 16 + 8 + j][pxl];
        u16 h = f2bf(v); h1[j] = h; l1[j] = f2bf(v - bf2f(h));
    }
    size_t dst = (((size_t)b * 66 + y + 1) * 66 + (pxl + 1)) * 512 + cb * 64 + cg * 16;
    *(u16x8*)(xh + dst) = h0;  *(u16x8*)(xh + dst + 8) = h1;
    *(u16x8*)(xl + dst) = l0;  *(u16x8*)(xl + dst + 8) = l1;
}

// ---------------------------------------------------------------------------
// Fused conv3x3+BN+ReLU as implicit GEMM, split-bf16, MFMA 32x32x16.
// Block: 256 thr (4 waves), tile 128oc x 128px (1 image-row-pair).
// K loop: 9 taps x CIN/32 chunks; LDS [kk][khalf][row][8ic] (conflict-free).
// z dim selects conv instance. PACKOUT: also emit padded hi/lo bf16 NHWC.
// ---------------------------------------------------------------------------
template <int CIN, bool PACKOUT>
__launch_bounds__(256)
__global__ void conv_mfma(const u16* __restrict__ xh0, const u16* __restrict__ xl0,
                          const u16* __restrict__ xh1, const u16* __restrict__ xl1,
                          const u16* __restrict__ wh0, const u16* __restrict__ wl0,
                          const u16* __restrict__ wh1, const u16* __restrict__ wl1,
                          const float* __restrict__ coef0, const float* __restrict__ coef1,
                          float* __restrict__ fo0, float* __restrict__ fo1,
                          u16* __restrict__ ph0, u16* __restrict__ pl0,
                          u16* __restrict__ ph1, u16* __restrict__ pl1) {
    constexpr int ICC = CIN / 32;
    constexpr int NT  = 9 * ICC;
    const int z = blockIdx.z;
    const u16* xh = z ? xh1 : xh0;  const u16* xl = z ? xl1 : xl0;
    const u16* wh = z ? wh1 : wh0;  const u16* wl = z ? wl1 : wl0;
    const float* coef = z ? coef1 : coef0;
    float* fo = z ? fo1 : fo0;
    u16* ph = z ? ph1 : ph0;  u16* pl = z ? pl1 : pl0;

    const int tile = blockIdx.x;          // 0..127
    const int b  = tile >> 5;
    const int y0 = (tile & 31) * 2;
    const int tid = threadIdx.x;

    __shared__ char smem[65536];          // 2 x 32KB double buffer

    // ---- staging bases (per thread). flat = i*256+tid -> buffer i>>1, kk=i&1,
    // row index = tid&127, khalf = tid>>7.  LDS dest linear: flat*16.
    const int cidx = tid & 127;
    const int khv  = (tid >> 7) & 1;
    const u16* bAh = wh + (size_t)cidx * CIN + khv * 8;
    const u16* bAl = wl + (size_t)cidx * CIN + khv * 8;
    const int rr = cidx >> 6, xxc = cidx & 63;
    const size_t rowoff = ((size_t)(b * 66 + y0 + rr) * 66 + xxc) * CIN + khv * 8;
    const u16* bBh = xh + rowoff;
    const u16* bBl = xl + rowoff;
    char* ldst = smem + (tid & 192) * 16;

    // ---- wave / fragment geometry
    const int wid = tid >> 6, lane = tid & 63;
    const int wr = wid >> 1, wc = wid & 1;
    const int l31 = lane & 31, lhi = lane >> 5;
    const int laneA = (lhi * 128 + wr * 64 + l31) * 16;          // + kk*4096 + m*512
    const int laneB = 16384 + (lhi * 128 + wc * 64 + l31) * 16;  // + kk*4096 + n*512

    f32x16 acc[2][2];
#pragma unroll
    for (int m = 0; m < 2; m++)
#pragma unroll
        for (int n = 0; n < 2; n++)
#pragma unroll
            for (int r = 0; r < 16; r++) acc[m][n][r] = 0.0f;

    auto stage = [&](int t, int db) {
        const int tap = t / ICC;
        const int ic0 = (t % ICC) * 32;
        const int offA = tap * 128 * CIN + ic0;
        const int offB = ((tap / 3) * 66 + (tap % 3)) * CIN + ic0;
        char* ld = ldst + db * 32768;
        gl_lds16(bAh + offA,      ld);
        gl_lds16(bAh + offA + 16, ld + 4096);
        gl_lds16(bAl + offA,      ld + 8192);
        gl_lds16(bAl + offA + 16, ld + 12288);
        gl_lds16(bBh + offB,      ld + 16384);
        gl_lds16(bBh + offB + 16, ld + 20480);
        gl_lds16(bBl + offB,      ld + 24576);
        gl_lds16(bBl + offB + 16, ld + 28672);
    };

    stage(0, 0);
    __syncthreads();

    for (int t = 0; t < NT; ++t) {
        const int db = t & 1;
        if (t + 1 < NT) stage(t + 1, db ^ 1);
        const char* sb = smem + db * 32768;

        bf16x8 Ah[2][2], Al[2][2], Bh[2][2], Bl[2][2];
#pragma unroll
        for (int kk = 0; kk < 2; kk++)
#pragma unroll
            for (int m = 0; m < 2; m++) {
                Ah[m][kk] = *(const bf16x8*)(sb + laneA + kk * 4096 + m * 512);
                Al[m][kk] = *(const bf16x8*)(sb + 8192 + laneA + kk * 4096 + m * 512);
            }
#pragma unroll
        for (int kk = 0; kk < 2; kk++)
#pragma unroll
            for (int n = 0; n < 2; n++) {
                Bh[n][kk] = *(const bf16x8*)(sb + laneB + kk * 4096 + n * 512);
                Bl[n][kk] = *(const bf16x8*)(sb + 8192 + laneB + kk * 4096 + n * 512);
            }
#pragma unroll
        for (int m = 0; m < 2; m++)
#pragma unroll
            for (int n = 0; n < 2; n++)
#pragma unroll
                for (int kk = 0; kk < 2; kk++) {
                    acc[m][n] = __builtin_amdgcn_mfma_f32_32x32x16_bf16(Ah[m][kk], Bh[n][kk], acc[m][n], 0, 0, 0);
                    acc[m][n] = __builtin_amdgcn_mfma_f32_32x32x16_bf16(Ah[m][kk], Bl[n][kk], acc[m][n], 0, 0, 0);
                    acc[m][n] = __builtin_amdgcn_mfma_f32_32x32x16_bf16(Al[m][kk], Bh[n][kk], acc[m][n], 0, 0, 0);
                }
        __syncthreads();
    }

    // ---- epilogue: BN + ReLU, write fp32 NHWC (+ optional padded hi/lo pack)
#pragma unroll
    for (int n = 0; n < 2; n++) {
        const int pxl = wc * 64 + n * 32 + l31;
        const int pxg = tile * 128 + pxl;
        const int bb = pxg >> 12, yy = (pxg >> 6) & 63, xg = pxg & 63;
        const size_t fbase = (size_t)pxg * 128;
        const size_t pbase = (((size_t)bb * 66 + yy + 1) * 66 + (xg + 1)) * 128;
#pragma unroll
        for (int m = 0; m < 2; m++)
#pragma unroll
            for (int q = 0; q < 4; q++) {
                const int oc4 = wr * 64 + m * 32 + q * 8 + lhi * 4;
                f32x4 sc = *(const f32x4*)&coef[oc4];
                f32x4 sh = *(const f32x4*)&coef[128 + oc4];
                f32x4 outv;
                u16x4 hv, lv;
#pragma unroll
                for (int j = 0; j < 4; j++) {
                    float v = acc[m][n][q * 4 + j] * sc[j] + sh[j];
                    v = v > 0.0f ? v : 0.0f;
                    outv[j] = v;
                    if (PACKOUT) {
                        u16 h = f2bf(v);
                        hv[j] = h;
                        lv[j] = f2bf(v - bf2f(h));
                    }
                }
                *(f32x4*)&fo[fbase + oc4] = outv;
                if (PACKOUT) {
                    *(u16x4*)&ph[pbase + oc4] = hv;
                    *(u16x4*)&pl[pbase + oc4] = lv;
                }
            }
    }
}

// ---------------- final 1x1 conv: (b3a+b3b) NHWC -> out NCHW [4][19][4096] ---
__launch_bounds__(256)
__global__ void conv1x1(const float* __restrict__ fa, const float* __restrict__ fb,
                        const float* __restrict__ w8, const float* __restrict__ b8,
                        float* __restrict__ out) {
    __shared__ float s_w[128 * 20];
    int tid = threadIdx.x;
    for (int i = tid; i < 19 * 128; i += 256) {
        int o = i >> 7, c = i & 127;
        s_w[c * 20 + o] = w8[i];
    }
    __syncthreads();
    size_t px = (size_t)blockIdx.x * 256 + tid;
    const f32x4* A = (const f32x4*)(fa + px * 128);
    const f32x4* B = (const f32x4*)(fb + px * 128);
    float acc[19];
#pragma unroll
    for (int o = 0; o < 19; o++) acc[o] = 0.0f;
    for (int cq = 0; cq < 32; cq++) {
        f32x4 v = A[cq] + B[cq];
#pragma unroll
        for (int j = 0; j < 4; j++) {
            float iv = v[j];
            int c = cq * 4 + j;
#pragma unroll
            for (int o = 0; o < 19; o++) acc[o] += iv * s_w[c * 20 + o];
        }
    }
    int b = px >> 12, n = px & 4095;
#pragma unroll
    for (int o = 0; o < 19; o++)
        out[((size_t)b * 19 + o) * 4096 + n] = acc[o] + b8[o];
}

// ================= guarded fallback path (gamma != 0; dead in bench) =========

__global__ void lin_q(const float* __restrict__ g, const float* __restrict__ feat,
                      const float* __restrict__ qw, const float* __restrict__ qb,
                      float* __restrict__ outq) {
    if (g[0] == 0.0f) return;
    __shared__ float s_w[16 * 128];
    int tid = threadIdx.x;
    for (int i = tid; i < 2048; i += 256) s_w[i] = qw[i];
    __syncthreads();
    size_t px = (size_t)blockIdx.x * 256 + tid;
    const float* in = feat + px * 128;
    float acc[16];
#pragma unroll
    for (int o = 0; o < 16; o++) acc[o] = 0.0f;
    for (int c = 0; c < 128; c++) {
        float iv = in[c];
#pragma unroll
        for (int o = 0; o < 16; o++) acc[o] += iv * s_w[o * 128 + c];
    }
#pragma unroll
    for (int o = 0; o < 16; o++) outq[px * 16 + o] = acc[o] + qb[o];
}

__global__ void lin_v(const float* __restrict__ g, const float* __restrict__ feat,
                      const float* __restrict__ vw, const float* __restrict__ vb,
                      float* __restrict__ outv) {
    if (g[0] == 0.0f) return;
    int tid = threadIdx.x;
    size_t px = (size_t)blockIdx.x * 64 + (tid >> 2);
    int q4 = tid & 3;
    const float* in = feat + px * 128;
    float acc[32];
#pragma unroll
    for (int j = 0; j < 32; j++) acc[j] = 0.0f;
    for (int c = 0; c < 128; c++) {
        float iv = in[c];
        for (int j = 0; j < 32; j++) acc[j] += iv * vw[(size_t)(q4 * 32 + j) * 128 + c];
    }
    for (int j = 0; j < 32; j++)
        outv[px * 128 + q4 * 32 + j] = acc[j] + vb[q4 * 32 + j];
}

// one block handles 32 query pixels; overwrites xpad1 hi/lo with sa_feat
__global__ void sa_attn(const float* __restrict__ g, const float* __restrict__ qb,
                        const float* __restrict__ vb, const float* __restrict__ feat1,
                        u16* __restrict__ ph, u16* __restrict__ pl) {
    if (g[0] == 0.0f) return;
    float gamma = g[0];
    int b = blockIdx.y, grp = blockIdx.x, tid = threadIdx.x;
    __shared__ float s_e[4096];
    __shared__ float s_red[256];
    __shared__ float s_q[16];
    __shared__ float s_o[256];
    for (int ni = 0; ni < 32; ni++) {
        int n = grp * 32 + ni;
        if (tid < 16) s_q[tid] = qb[((size_t)b * 4096 + n) * 16 + tid];
        __syncthreads();
        float lmax = -1e30f;
        for (int m = tid; m < 4096; m += 256) {
            const float* qm = qb + ((size_t)b * 4096 + m) * 16;
            float e = 0.0f;
#pragma unroll
            for (int k = 0; k < 16; k++) e += s_q[k] * qm[k];
            s_e[m] = e;
            lmax = fmaxf(lmax, e);
        }
        s_red[tid] = lmax;
        __syncthreads();
        for (int s = 128; s > 0; s >>= 1) {
            if (tid < s) s_red[tid] = fmaxf(s_red[tid], s_red[tid + s]);
            __syncthreads();
        }
        float mx = s_red[0];
        __syncthreads();
        float lsum = 0.0f;
        for (int m = tid; m < 4096; m += 256) {
            float p = expf(s_e[m] - mx);
            s_e[m] = p;
            lsum += p;
        }
        s_red[tid] = lsum;
        __syncthreads();
        for (int s = 128; s > 0; s >>= 1) {
            if (tid < s) s_red[tid] += s_red[tid + s];
            __syncthreads();
        }
        float denom = s_red[0];
        __syncthreads();
        int c = tid & 127, half = tid >> 7;
        float acc = 0.0f;
        for (int m = half * 2048; m < half * 2048 + 2048; m++)
            acc += s_e[m] * vb[((size_t)b * 4096 + m) * 128 + c];
        s_o[tid] = acc;
        __syncthreads();
        if (tid < 128) {
            float o = (s_o[tid] + s_o[tid + 128]) / denom;
            float val = feat1[((size_t)b * 4096 + n) * 128 + tid] + gamma * o;
            int yy = n >> 6, xx = n & 63;
            size_t pidx = (((size_t)b * 66 + yy + 1) * 66 + (xx + 1)) * 128 + tid;
            u16 h = f2bf(val);
            ph[pidx] = h;
            pl[pidx] = f2bf(val - bf2f(h));
        }
        __syncthreads();
    }
}

// one block per (b, channel-row c); overwrites xpad2 hi/lo with sc_feat
__global__ void ca_attn(const float* __restrict__ g, const float* __restrict__ feat2,
                        u16* __restrict__ ph, u16* __restrict__ pl) {
    if (g[0] == 0.0f) return;
    float gamma = g[0];
    int b = blockIdx.y, crow = blockIdx.x, d = threadIdx.x;   // 128 threads
    __shared__ float s_red[128];
    __shared__ float s_attn[128];
    const float* base = feat2 + (size_t)b * 4096 * 128;
    float e = 0.0f;
    for (int n = 0; n < 4096; n++) e += base[(size_t)n * 128 + crow] * base[(size_t)n * 128 + d];
    s_red[d] = e;
    __syncthreads();
    for (int s = 64; s > 0; s >>= 1) {
        if (d < s) s_red[d] = fmaxf(s_red[d], s_red[d + s]);
        __syncthreads();
    }
    float m1 = s_red[0];
    __syncthreads();
    float en = m1 - e;
    s_red[d] = en;
    __syncthreads();
    for (int s = 64; s > 0; s >>= 1) {
        if (d < s) s_red[d] = fmaxf(s_red[d], s_red[d + s]);
        __syncthreads();
    }
    float m2 = s_red[0];
    __syncthreads();
    float p = expf(en - m2);
    s_red[d] = p;
    __syncthreads();
    for (int s = 64; s > 0; s >>= 1) {
        if (d < s) s_red[d] += s_red[d + s];
        __syncthreads();
    }
    s_attn[d] = p / s_red[0];
    __syncthreads();
    for (int n = d; n < 4096; n += 128) {
        float acc = 0.0f;
#pragma unroll 8
        for (int dd = 0; dd < 128; dd++) acc += s_attn[dd] * base[(size_t)n * 128 + dd];
        float val = base[(size_t)n * 128 + crow] + gamma * acc;
        int yy = n >> 6, xx = n & 63;
        size_t pidx = (((size_t)b * 66 + yy + 1) * 66 + (xx + 1)) * 128 + crow;
        u16 h = f2bf(val);
        ph[pidx] = h;
        pl[pidx] = f2bf(val - bf2f(h));
    }
}

// ================================ launch =====================================
extern "C" void kernel_launch(void* const* d_in, const int* in_sizes, int n_in,
                              void* d_out, int out_size, void* d_ws, size_t ws_size,
                              hipStream_t stream) {
    const float* x      = (const float*)d_in[0];
    const float* w5a    = (const float*)d_in[1];
    const float* bn5a_s = (const float*)d_in[2];
    const float* bn5a_b = (const float*)d_in[3];
    const float* bn5a_m = (const float*)d_in[4];
    const float* bn5a_v = (const float*)d_in[5];
    const float* w5c    = (const float*)d_in[6];
    const float* bn5c_s = (const float*)d_in[7];
    const float* bn5c_b = (const float*)d_in[8];
    const float* bn5c_m = (const float*)d_in[9];
    const float* bn5c_v = (const float*)d_in[10];
    const float* q_w    = (const float*)d_in[11];
    const float* q_b    = (const float*)d_in[12];
    const float* v_w    = (const float*)d_in[13];
    const float* v_b    = (const float*)d_in[14];
    const float* g_sa   = (const float*)d_in[15];
    const float* g_sc   = (const float*)d_in[16];
    const float* w51    = (const float*)d_in[17];
    const float* bn51_s = (const float*)d_in[18];
    const float* bn51_b = (const float*)d_in[19];
    const float* bn51_m = (const float*)d_in[20];
    const float* bn51_v = (const float*)d_in[21];
    const float* w52    = (const float*)d_in[22];
    const float* bn52_s = (const float*)d_in[23];
    const float* bn52_b = (const float*)d_in[24];
    const float* bn52_m = (const float*)d_in[25];
    const float* bn52_v = (const float*)d_in[26];
    const float* w8     = (const float*)d_in[27];
    const float* b8     = (const float*)d_in[28];
    float* out = (float*)d_out;
    (void)in_sizes; (void)n_in; (void)out_size; (void)ws_size;

    // ---- workspace layout (bytes)
    char* W = (char*)d_ws;
    constexpr size_t XP0 = (size_t)4 * 66 * 66 * 512 * 2;   // 17,842,176
    constexpr size_t XP1 = (size_t)4 * 66 * 66 * 128 * 2;   //  4,460,544
    constexpr size_t WPA = (size_t)9 * 128 * 512 * 2;       //  1,179,648
    constexpr size_t WPB = (size_t)9 * 128 * 128 * 2;       //    294,912
    constexpr size_t FT  = (size_t)4 * 4096 * 128 * 4;      //  8,388,608
    size_t off = 0;
    u16* xp0h = (u16*)(W + off); off += XP0;
    u16* xp0l = (u16*)(W + off); off += XP0;
    u16* xp1h = (u16*)(W + off); off += XP1;
    u16* xp1l = (u16*)(W + off); off += XP1;
    u16* xp2h = (u16*)(W + off); off += XP1;
    u16* xp2l = (u16*)(W + off); off += XP1;
    u16* wp5ah = (u16*)(W + off); off += WPA;
    u16* wp5al = (u16*)(W + off); off += WPA;
    u16* wp5ch = (u16*)(W + off); off += WPA;
    u16* wp5cl = (u16*)(W + off); off += WPA;
    u16* wp51h = (u16*)(W + off); off += WPB;
    u16* wp51l = (u16*)(W + off); off += WPB;
    u16* wp52h = (u16*)(W + off); off += WPB;
    u16* wp52l = (u16*)(W + off); off += WPB;
    float* c5a = (float*)(W + off); off += 1024;
    float* c5c = (float*)(W + off); off += 1024;
    float* c51 = (float*)(W + off); off += 1024;
    float* c52 = (float*)(W + off); off += 1024;
    float* b0  = (float*)(W + off); off += FT;   // feat1 fp32 NHWC
    float* b1  = (float*)(W + off); off += FT;   // feat2 fp32 NHWC
    float* b3a = (float*)(W + off); off += FT;   // sa_conv
    float* b3b = (float*)(W + off); off += FT;   // sc_conv
    // fallback q/v buffers alias b3a/b3b (live ranges disjoint)
    float* qbuf = b3a;
    float* vbuf = (float*)((char*)b3a + 1048576);

    // ---- prep
    border_zero<<<dim3(1040, 3), 256, 0, stream>>>(xp0h, xp0l, xp1h, xp1l, xp2h, xp2l);
    bn_prep_all<<<4, 128, 0, stream>>>(bn5a_s, bn5a_b, bn5a_m, bn5a_v,
                                       bn5c_s, bn5c_b, bn5c_m, bn5c_v,
                                       bn51_s, bn51_b, bn51_m, bn51_v,
                                       bn52_s, bn52_b, bn52_m, bn52_v,
                                       c5a, c5c, c51, c52);
    pack_w<512><<<dim3(2304, 1, 2), 256, 0, stream>>>(w5a, wp5ah, wp5al, w5c, wp5ch, wp5cl);
    pack_w<128><<<dim3(576, 1, 2), 256, 0, stream>>>(w51, wp51h, wp51l, w52, wp52h, wp52l);
    pack_x<<<dim3(8, 64, 4), 256, 0, stream>>>(x, xp0h, xp0l);

    // ---- feat1 = CBR(x,5a) [z=0], feat2 = CBR(x,5c) [z=1]; epilogue packs
    // the padded hi/lo inputs for conv51/conv52.
    conv_mfma<512, true><<<dim3(128, 1, 2), 256, 0, stream>>>(
        xp0h, xp0l, xp0h, xp0l,
        wp5ah, wp5al, wp5ch, wp5cl,
        c5a, c5c, b0, b1,
        xp1h, xp1l, xp2h, xp2l);

    // ---- guarded attention (no-ops when gamma == 0); overwrite staged inputs
    lin_q<<<64, 256, 0, stream>>>(g_sa, b0, q_w, q_b, qbuf);
    lin_v<<<256, 256, 0, stream>>>(g_sa, b0, v_w, v_b, vbuf);
    sa_attn<<<dim3(128, 4), 256, 0, stream>>>(g_sa, qbuf, vbuf, b0, xp1h, xp1l);
    ca_attn<<<dim3(128, 4), 128, 0, stream>>>(g_sc, b1, xp2h, xp2l);

    // ---- sa_conv = CBR(sa_feat,51) [z=0], sc_conv = CBR(sc_feat,52) [z=1]
    conv_mfma<128, false><<<dim3(128, 1, 2), 256, 0, stream>>>(
        xp1h, xp1l, xp2h, xp2l,
        wp51h, wp51l, wp52h, wp52l,
        c51, c52, b3a, b3b,
        nullptr, nullptr, nullptr, nullptr);

    // ---- out = 1x1(b3a + b3b) + bias, NCHW
    conv1x1<<<64, 256, 0, stream>>>(b3a, b3b, w8, b8, out);
}

// Round 4
// 364.641 us; speedup vs baseline: 4.9892x; 1.1335x over previous
//
#include <hip/hip_runtime.h>
#include <math.h>

#define EPS 1e-5f

// ---------------------------------------------------------------------------
// SegHead on MI355X via split-precision bf16 MFMA implicit-GEMM convs.
// gamma_sa/gamma_sc == 0 in bench inputs -> attention guarded device-side.
// fp32 value v is split v = hi + lo (both bf16); A*B uses 3 MFMA terms
// (hh, hl, lh), dropping lo*lo (~2^-18 relative) -> fp32-grade accuracy.
// R3: counted-vmcnt pipeline (T4): raw s_barrier + s_waitcnt vmcnt(8) keeps
// next tile's global_load_lds in flight across the barrier (no vmcnt(0)
// drain per K-step). Two raw barriers/iter fence LDS buffer reuse.
// ---------------------------------------------------------------------------

typedef unsigned int uint;
typedef unsigned short u16;
typedef u16 u16x4 __attribute__((ext_vector_type(4)));
typedef u16 u16x8 __attribute__((ext_vector_type(8)));
typedef __bf16 bf16x8 __attribute__((ext_vector_type(8)));
typedef float f32x4 __attribute__((ext_vector_type(4)));
typedef float f32x16 __attribute__((ext_vector_type(16)));

#define WAIT_VM8() asm volatile("s_waitcnt vmcnt(8)" ::: "memory")
#define WAIT_VM0() asm volatile("s_waitcnt vmcnt(0)" ::: "memory")
#define BARRIER()  asm volatile("s_barrier" ::: "memory")

__device__ __forceinline__ u16 f2bf(float f) {
    uint u = __float_as_uint(f);
    u = u + 0x7FFF + ((u >> 16) & 1);   // RNE
    return (u16)(u >> 16);
}
__device__ __forceinline__ float bf2f(u16 h) {
    return __uint_as_float(((uint)h) << 16);
}

__device__ __forceinline__ void gl_lds16(const void* g, void* l) {
    __builtin_amdgcn_global_load_lds(
        (const __attribute__((address_space(1))) unsigned int*)g,
        (__attribute__((address_space(3))) unsigned int*)l, 16, 0, 0);
}

// ---------------- bn coefficients for all 4 convs in one launch ---------------
__global__ void bn_prep_all(const float* s0, const float* b0, const float* m0, const float* v0,
                            const float* s1, const float* b1, const float* m1, const float* v1,
                            const float* s2, const float* b2, const float* m2, const float* v2,
                            const float* s3, const float* b3, const float* m3, const float* v3,
                            float* c0, float* c1, float* c2, float* c3) {
    int k = blockIdx.x, i = threadIdx.x;
    const float *s, *bb, *mm, *vv; float* cf;
    if (k == 0)      { s = s0; bb = b0; mm = m0; vv = v0; cf = c0; }
    else if (k == 1) { s = s1; bb = b1; mm = m1; vv = v1; cf = c1; }
    else if (k == 2) { s = s2; bb = b2; mm = m2; vv = v2; cf = c2; }
    else             { s = s3; bb = b3; mm = m3; vv = v3; cf = c3; }
    float inv = s[i] / sqrtf(vv[i] + EPS);
    cf[i] = inv;
    cf[128 + i] = bb[i] - mm[i] * inv;
}

// ---------------- zero the 1-px borders of the padded NHWC bf16 buffers ------
__global__ void border_zero(u16* x0h, u16* x0l, u16* x1h, u16* x1l, u16* x2h, u16* x2l) {
    int p = blockIdx.x;            // 0..1039 (260 border px * 4 images)
    int img = p / 260, pe = p % 260;
    int y, x;
    if (pe < 66)       { y = 0;  x = pe; }
    else if (pe < 132) { y = 65; x = pe - 66; }
    else { int q = pe - 132; y = 1 + (q >> 1); x = (q & 1) * 65; }
    int buf = blockIdx.y, tid = threadIdx.x;
    if (buf == 0) {
        size_t base = (((size_t)img * 66 + y) * 66 + x) * 512;
        for (int c = tid; c < 512; c += 256) { x0h[base + c] = 0; x0l[base + c] = 0; }
    } else {
        u16* hh = (buf == 1) ? x1h : x2h;
        u16* ll = (buf == 1) ? x1l : x2l;
        size_t base = (((size_t)img * 66 + y) * 66 + x) * 128;
        for (int c = tid; c < 128; c += 256) { hh[base + c] = 0; ll[base + c] = 0; }
    }
}

// ---------------- weights: [O=128][CIN][3][3] fp32 -> [tap][oc][ic] hi/lo ----
template <int CIN>
__global__ void pack_w(const float* __restrict__ w0, u16* __restrict__ h0, u16* __restrict__ l0,
                       const float* __restrict__ w1, u16* __restrict__ h1, u16* __restrict__ l1) {
    const float* w = blockIdx.z ? w1 : w0;
    u16* hh = blockIdx.z ? h1 : h0;
    u16* ll = blockIdx.z ? l1 : l0;
    int i = blockIdx.x * 256 + threadIdx.x;      // == dst index (tap*128+oc)*CIN+ic
    int ic = i & (CIN - 1);
    int rest = i / CIN;
    int oc = rest & 127;
    int tap = rest >> 7;
    float f = w[((size_t)oc * CIN + ic) * 9 + tap];
    u16 h = f2bf(f);
    hh[i] = h;
    ll[i] = f2bf(f - bf2f(h));
}

// ---------------- x: [4][512][64][64] fp32 NCHW -> padded NHWC hi/lo bf16 ----
__global__ void pack_x(const float* __restrict__ x, u16* __restrict__ xh, u16* __restrict__ xl) {
    __shared__ float tile[64][68];
    int cb = blockIdx.x, y = blockIdx.y, b = blockIdx.z, tid = threadIdx.x;
    int cl = tid >> 2, seg = tid & 3;
    const float* src = x + (((size_t)b * 512 + cb * 64 + cl) * 64 + y) * 64 + seg * 16;
#pragma unroll
    for (int j = 0; j < 4; j++)
        *(f32x4*)&tile[cl][seg * 16 + j * 4] = *(const f32x4*)(src + j * 4);
    __syncthreads();
    int pxl = tid >> 2, cg = tid & 3;
    u16x8 h0, h1, l0, l1;
#pragma unroll
    for (int j = 0; j < 8; j++) {
        float v = tile[cg * 16 + j][pxl];
        u16 h = f2bf(v); h0[j] = h; l0[j] = f2bf(v - bf2f(h));
    }
#pragma unroll
    for (int j = 0; j < 8; j++) {
        float v = tile[cg * 16 + 8 + j][pxl];
        u16 h = f2bf(v); h1[j] = h; l1[j] = f2bf(v - bf2f(h));
    }
    size_t dst = (((size_t)b * 66 + y + 1) * 66 + (pxl + 1)) * 512 + cb * 64 + cg * 16;
    *(u16x8*)(xh + dst) = h0;  *(u16x8*)(xh + dst + 8) = h1;
    *(u16x8*)(xl + dst) = l0;  *(u16x8*)(xl + dst + 8) = l1;
}

// ---------------------------------------------------------------------------
// Fused conv3x3+BN+ReLU as implicit GEMM, split-bf16, MFMA 32x32x16.
// Block: 256 thr (4 waves), tile 128oc x 128px (1 image-row-pair).
// K loop: 9 taps x CIN/32 chunks; LDS [kk][khalf][row][8ic] (conflict-free).
// Counted-vmcnt double-buffer pipeline; z dim selects conv instance.
// PACKOUT: also emit padded hi/lo bf16 NHWC for the next conv stage.
// ---------------------------------------------------------------------------
template <int CIN, bool PACKOUT>
__launch_bounds__(256)
__global__ void conv_mfma(const u16* __restrict__ xh0, const u16* __restrict__ xl0,
                          const u16* __restrict__ xh1, const u16* __restrict__ xl1,
                          const u16* __restrict__ wh0, const u16* __restrict__ wl0,
                          const u16* __restrict__ wh1, const u16* __restrict__ wl1,
                          const float* __restrict__ coef0, const float* __restrict__ coef1,
                          float* __restrict__ fo0, float* __restrict__ fo1,
                          u16* __restrict__ ph0, u16* __restrict__ pl0,
                          u16* __restrict__ ph1, u16* __restrict__ pl1) {
    constexpr int ICC = CIN / 32;
    constexpr int NT  = 9 * ICC;
    const int z = blockIdx.z;
    const u16* xh = z ? xh1 : xh0;  const u16* xl = z ? xl1 : xl0;
    const u16* wh = z ? wh1 : wh0;  const u16* wl = z ? wl1 : wl0;
    const float* coef = z ? coef1 : coef0;
    float* fo = z ? fo1 : fo0;
    u16* ph = z ? ph1 : ph0;  u16* pl = z ? pl1 : pl0;

    const int tile = blockIdx.x;          // 0..127
    const int b  = tile >> 5;
    const int y0 = (tile & 31) * 2;
    const int tid = threadIdx.x;

    __shared__ char smem[65536];          // 2 x 32KB double buffer

    // ---- staging bases (per thread). LDS dest is wave-uniform base + lane*16.
    const int cidx = tid & 127;
    const int khv  = (tid >> 7) & 1;
    const u16* bAh = wh + (size_t)cidx * CIN + khv * 8;
    const u16* bAl = wl + (size_t)cidx * CIN + khv * 8;
    const int rr = cidx >> 6, xxc = cidx & 63;
    const size_t rowoff = ((size_t)(b * 66 + y0 + rr) * 66 + xxc) * CIN + khv * 8;
    const u16* bBh = xh + rowoff;
    const u16* bBl = xl + rowoff;
    char* ldst = smem + (tid & 192) * 16;

    // ---- wave / fragment geometry
    const int wid = tid >> 6, lane = tid & 63;
    const int wr = wid >> 1, wc = wid & 1;
    const int l31 = lane & 31, lhi = lane >> 5;
    const int laneA = (lhi * 128 + wr * 64 + l31) * 16;          // + kk*4096 + m*512
    const int laneB = 16384 + (lhi * 128 + wc * 64 + l31) * 16;  // + kk*4096 + n*512

    f32x16 acc[2][2];
#pragma unroll
    for (int m = 0; m < 2; m++)
#pragma unroll
        for (int n = 0; n < 2; n++)
#pragma unroll
            for (int r = 0; r < 16; r++) acc[m][n][r] = 0.0f;

    auto stage = [&](int t, int db) {
        const int tap = t / ICC;
        const int ic0 = (t % ICC) * 32;
        const int offA = tap * 128 * CIN + ic0;
        const int offB = ((tap / 3) * 66 + (tap % 3)) * CIN + ic0;
        char* ld = ldst + db * 32768;
        gl_lds16(bAh + offA,      ld);
        gl_lds16(bAh + offA + 16, ld + 4096);
        gl_lds16(bAl + offA,      ld + 8192);
        gl_lds16(bAl + offA + 16, ld + 12288);
        gl_lds16(bBh + offB,      ld + 16384);
        gl_lds16(bBh + offB + 16, ld + 20480);
        gl_lds16(bBl + offB,      ld + 24576);
        gl_lds16(bBl + offB + 16, ld + 28672);
    };

    stage(0, 0);

    for (int t = 0; t < NT; ++t) {
        const int db = t & 1;
        // issue next tile's loads (stay in flight across the barrier), then
        // wait for THIS tile's 8 loads only (counted vmcnt), then rendezvous.
        if (t + 1 < NT) {
            stage(t + 1, db ^ 1);
            WAIT_VM8();
        } else {
            WAIT_VM0();
        }
        BARRIER();    // all waves' tile-t loads have landed in LDS

        const char* sb = smem + db * 32768;

        bf16x8 Ah[2][2], Al[2][2], Bh[2][2], Bl[2][2];
#pragma unroll
        for (int kk = 0; kk < 2; kk++)
#pragma unroll
            for (int m = 0; m < 2; m++) {
                Ah[m][kk] = *(const bf16x8*)(sb + laneA + kk * 4096 + m * 512);
                Al[m][kk] = *(const bf16x8*)(sb + 8192 + laneA + kk * 4096 + m * 512);
            }
#pragma unroll
        for (int kk = 0; kk < 2; kk++)
#pragma unroll
            for (int n = 0; n < 2; n++) {
                Bh[n][kk] = *(const bf16x8*)(sb + laneB + kk * 4096 + n * 512);
                Bl[n][kk] = *(const bf16x8*)(sb + 8192 + laneB + kk * 4096 + n * 512);
            }
        __builtin_amdgcn_s_setprio(1);
#pragma unroll
        for (int m = 0; m < 2; m++)
#pragma unroll
            for (int n = 0; n < 2; n++)
#pragma unroll
                for (int kk = 0; kk < 2; kk++) {
                    acc[m][n] = __builtin_amdgcn_mfma_f32_32x32x16_bf16(Ah[m][kk], Bh[n][kk], acc[m][n], 0, 0, 0);
                    acc[m][n] = __builtin_amdgcn_mfma_f32_32x32x16_bf16(Ah[m][kk], Bl[n][kk], acc[m][n], 0, 0, 0);
                    acc[m][n] = __builtin_amdgcn_mfma_f32_32x32x16_bf16(Al[m][kk], Bh[n][kk], acc[m][n], 0, 0, 0);
                }
        __builtin_amdgcn_s_setprio(0);
        BARRIER();    // all waves done reading buf[db]; next iter may overwrite it
    }

    // ---- epilogue: BN + ReLU, write fp32 NHWC (+ optional padded hi/lo pack)
#pragma unroll
    for (int n = 0; n < 2; n++) {
        const int pxl = wc * 64 + n * 32 + l31;
        const int pxg = tile * 128 + pxl;
        const int bb = pxg >> 12, yy = (pxg >> 6) & 63, xg = pxg & 63;
        const size_t fbase = (size_t)pxg * 128;
        const size_t pbase = (((size_t)bb * 66 + yy + 1) * 66 + (xg + 1)) * 128;
#pragma unroll
        for (int m = 0; m < 2; m++)
#pragma unroll
            for (int q = 0; q < 4; q++) {
                const int oc4 = wr * 64 + m * 32 + q * 8 + lhi * 4;
                f32x4 sc = *(const f32x4*)&coef[oc4];
                f32x4 sh = *(const f32x4*)&coef[128 + oc4];
                f32x4 outv;
                u16x4 hv, lv;
#pragma unroll
                for (int j = 0; j < 4; j++) {
                    float v = acc[m][n][q * 4 + j] * sc[j] + sh[j];
                    v = v > 0.0f ? v : 0.0f;
                    outv[j] = v;
                    if (PACKOUT) {
                        u16 h = f2bf(v);
                        hv[j] = h;
                        lv[j] = f2bf(v - bf2f(h));
                    }
                }
                *(f32x4*)&fo[fbase + oc4] = outv;
                if (PACKOUT) {
                    *(u16x4*)&ph[pbase + oc4] = hv;
                    *(u16x4*)&pl[pbase + oc4] = lv;
                }
            }
    }
}

// ---------------- final 1x1 conv: (b3a+b3b) NHWC -> out NCHW [4][19][4096] ---
__launch_bounds__(256)
__global__ void conv1x1(const float* __restrict__ fa, const float* __restrict__ fb,
                        const float* __restrict__ w8, const float* __restrict__ b8,
                        float* __restrict__ out) {
    __shared__ float s_w[128 * 20];
    int tid = threadIdx.x;
    for (int i = tid; i < 19 * 128; i += 256) {
        int o = i >> 7, c = i & 127;
        s_w[c * 20 + o] = w8[i];
    }
    __syncthreads();
    size_t px = (size_t)blockIdx.x * 256 + tid;
    const f32x4* A = (const f32x4*)(fa + px * 128);
    const f32x4* B = (const f32x4*)(fb + px * 128);
    float acc[19];
#pragma unroll
    for (int o = 0; o < 19; o++) acc[o] = 0.0f;
    for (int cq = 0; cq < 32; cq++) {
        f32x4 v = A[cq] + B[cq];
#pragma unroll
        for (int j = 0; j < 4; j++) {
            float iv = v[j];
            int c = cq * 4 + j;
#pragma unroll
            for (int o = 0; o < 19; o++) acc[o] += iv * s_w[c * 20 + o];
        }
    }
    int b = px >> 12, n = px & 4095;
#pragma unroll
    for (int o = 0; o < 19; o++)
        out[((size_t)b * 19 + o) * 4096 + n] = acc[o] + b8[o];
}

// ================= guarded fallback path (gamma != 0; dead in bench) =========

__global__ void lin_q(const float* __restrict__ g, const float* __restrict__ feat,
                      const float* __restrict__ qw, const float* __restrict__ qb,
                      float* __restrict__ outq) {
    if (g[0] == 0.0f) return;
    __shared__ float s_w[16 * 128];
    int tid = threadIdx.x;
    for (int i = tid; i < 2048; i += 256) s_w[i] = qw[i];
    __syncthreads();
    size_t px = (size_t)blockIdx.x * 256 + tid;
    const float* in = feat + px * 128;
    float acc[16];
#pragma unroll
    for (int o = 0; o < 16; o++) acc[o] = 0.0f;
    for (int c = 0; c < 128; c++) {
        float iv = in[c];
#pragma unroll
        for (int o = 0; o < 16; o++) acc[o] += iv * s_w[o * 128 + c];
    }
#pragma unroll
    for (int o = 0; o < 16; o++) outq[px * 16 + o] = acc[o] + qb[o];
}

__global__ void lin_v(const float* __restrict__ g, const float* __restrict__ feat,
                      const float* __restrict__ vw, const float* __restrict__ vb,
                      float* __restrict__ outv) {
    if (g[0] == 0.0f) return;
    int tid = threadIdx.x;
    size_t px = (size_t)blockIdx.x * 64 + (tid >> 2);
    int q4 = tid & 3;
    const float* in = feat + px * 128;
    float acc[32];
#pragma unroll
    for (int j = 0; j < 32; j++) acc[j] = 0.0f;
    for (int c = 0; c < 128; c++) {
        float iv = in[c];
        for (int j = 0; j < 32; j++) acc[j] += iv * vw[(size_t)(q4 * 32 + j) * 128 + c];
    }
    for (int j = 0; j < 32; j++)
        outv[px * 128 + q4 * 32 + j] = acc[j] + vb[q4 * 32 + j];
}

// one block handles 32 query pixels; overwrites xpad1 hi/lo with sa_feat
__global__ void sa_attn(const float* __restrict__ g, const float* __restrict__ qb,
                        const float* __restrict__ vb, const float* __restrict__ feat1,
                        u16* __restrict__ ph, u16* __restrict__ pl) {
    if (g[0] == 0.0f) return;
    float gamma = g[0];
    int b = blockIdx.y, grp = blockIdx.x, tid = threadIdx.x;
    __shared__ float s_e[4096];
    __shared__ float s_red[256];
    __shared__ float s_q[16];
    __shared__ float s_o[256];
    for (int ni = 0; ni < 32; ni++) {
        int n = grp * 32 + ni;
        if (tid < 16) s_q[tid] = qb[((size_t)b * 4096 + n) * 16 + tid];
        __syncthreads();
        float lmax = -1e30f;
        for (int m = tid; m < 4096; m += 256) {
            const float* qm = qb + ((size_t)b * 4096 + m) * 16;
            float e = 0.0f;
#pragma unroll
            for (int k = 0; k < 16; k++) e += s_q[k] * qm[k];
            s_e[m] = e;
            lmax = fmaxf(lmax, e);
        }
        s_red[tid] = lmax;
        __syncthreads();
        for (int s = 128; s > 0; s >>= 1) {
            if (tid < s) s_red[tid] = fmaxf(s_red[tid], s_red[tid + s]);
            __syncthreads();
        }
        float mx = s_red[0];
        __syncthreads();
        float lsum = 0.0f;
        for (int m = tid; m < 4096; m += 256) {
            float p = expf(s_e[m] - mx);
            s_e[m] = p;
            lsum += p;
        }
        s_red[tid] = lsum;
        __syncthreads();
        for (int s = 128; s > 0; s >>= 1) {
            if (tid < s) s_red[tid] += s_red[tid + s];
            __syncthreads();
        }
        float denom = s_red[0];
        __syncthreads();
        int c = tid & 127, half = tid >> 7;
        float acc = 0.0f;
        for (int m = half * 2048; m < half * 2048 + 2048; m++)
            acc += s_e[m] * vb[((size_t)b * 4096 + m) * 128 + c];
        s_o[tid] = acc;
        __syncthreads();
        if (tid < 128) {
            float o = (s_o[tid] + s_o[tid + 128]) / denom;
            float val = feat1[((size_t)b * 4096 + n) * 128 + tid] + gamma * o;
            int yy = n >> 6, xx = n & 63;
            size_t pidx = (((size_t)b * 66 + yy + 1) * 66 + (xx + 1)) * 128 + tid;
            u16 h = f2bf(val);
            ph[pidx] = h;
            pl[pidx] = f2bf(val - bf2f(h));
        }
        __syncthreads();
    }
}

// one block per (b, channel-row c); overwrites xpad2 hi/lo with sc_feat
__global__ void ca_attn(const float* __restrict__ g, const float* __restrict__ feat2,
                        u16* __restrict__ ph, u16* __restrict__ pl) {
    if (g[0] == 0.0f) return;
    float gamma = g[0];
    int b = blockIdx.y, crow = blockIdx.x, d = threadIdx.x;   // 128 threads
    __shared__ float s_red[128];
    __shared__ float s_attn[128];
    const float* base = feat2 + (size_t)b * 4096 * 128;
    float e = 0.0f;
    for (int n = 0; n < 4096; n++) e += base[(size_t)n * 128 + crow] * base[(size_t)n * 128 + d];
    s_red[d] = e;
    __syncthreads();
    for (int s = 64; s > 0; s >>= 1) {
        if (d < s) s_red[d] = fmaxf(s_red[d], s_red[d + s]);
        __syncthreads();
    }
    float m1 = s_red[0];
    __syncthreads();
    float en = m1 - e;
    s_red[d] = en;
    __syncthreads();
    for (int s = 64; s > 0; s >>= 1) {
        if (d < s) s_red[d] = fmaxf(s_red[d], s_red[d + s]);
        __syncthreads();
    }
    float m2 = s_red[0];
    __syncthreads();
    float p = expf(en - m2);
    s_red[d] = p;
    __syncthreads();
    for (int s = 64; s > 0; s >>= 1) {
        if (d < s) s_red[d] += s_red[d + s];
        __syncthreads();
    }
    s_attn[d] = p / s_red[0];
    __syncthreads();
    for (int n = d; n < 4096; n += 128) {
        float acc = 0.0f;
#pragma unroll 8
        for (int dd = 0; dd < 128; dd++) acc += s_attn[dd] * base[(size_t)n * 128 + dd];
        float val = base[(size_t)n * 128 + crow] + gamma * acc;
        int yy = n >> 6, xx = n & 63;
        size_t pidx = (((size_t)b * 66 + yy + 1) * 66 + (xx + 1)) * 128 + crow;
        u16 h = f2bf(val);
        ph[pidx] = h;
        pl[pidx] = f2bf(val - bf2f(h));
    }
}

// ================================ launch =====================================
extern "C" void kernel_launch(void* const* d_in, const int* in_sizes, int n_in,
                              void* d_out, int out_size, void* d_ws, size_t ws_size,
                              hipStream_t stream) {
    const float* x      = (const float*)d_in[0];
    const float* w5a    = (const float*)d_in[1];
    const float* bn5a_s = (const float*)d_in[2];
    const float* bn5a_b = (const float*)d_in[3];
    const float* bn5a_m = (const float*)d_in[4];
    const float* bn5a_v = (const float*)d_in[5];
    const float* w5c    = (const float*)d_in[6];
    const float* bn5c_s = (const float*)d_in[7];
    const float* bn5c_b = (const float*)d_in[8];
    const float* bn5c_m = (const float*)d_in[9];
    const float* bn5c_v = (const float*)d_in[10];
    const float* q_w    = (const float*)d_in[11];
    const float* q_b    = (const float*)d_in[12];
    const float* v_w    = (const float*)d_in[13];
    const float* v_b    = (const float*)d_in[14];
    const float* g_sa   = (const float*)d_in[15];
    const float* g_sc   = (const float*)d_in[16];
    const float* w51    = (const float*)d_in[17];
    const float* bn51_s = (const float*)d_in[18];
    const float* bn51_b = (const float*)d_in[19];
    const float* bn51_m = (const float*)d_in[20];
    const float* bn51_v = (const float*)d_in[21];
    const float* w52    = (const float*)d_in[22];
    const float* bn52_s = (const float*)d_in[23];
    const float* bn52_b = (const float*)d_in[24];
    const float* bn52_m = (const float*)d_in[25];
    const float* bn52_v = (const float*)d_in[26];
    const float* w8     = (const float*)d_in[27];
    const float* b8     = (const float*)d_in[28];
    float* out = (float*)d_out;
    (void)in_sizes; (void)n_in; (void)out_size; (void)ws_size;

    // ---- workspace layout (bytes)
    char* W = (char*)d_ws;
    constexpr size_t XP0 = (size_t)4 * 66 * 66 * 512 * 2;   // 17,842,176
    constexpr size_t XP1 = (size_t)4 * 66 * 66 * 128 * 2;   //  4,460,544
    constexpr size_t WPA = (size_t)9 * 128 * 512 * 2;       //  1,179,648
    constexpr size_t WPB = (size_t)9 * 128 * 128 * 2;       //    294,912
    constexpr size_t FT  = (size_t)4 * 4096 * 128 * 4;      //  8,388,608
    size_t off = 0;
    u16* xp0h = (u16*)(W + off); off += XP0;
    u16* xp0l = (u16*)(W + off); off += XP0;
    u16* xp1h = (u16*)(W + off); off += XP1;
    u16* xp1l = (u16*)(W + off); off += XP1;
    u16* xp2h = (u16*)(W + off); off += XP1;
    u16* xp2l = (u16*)(W + off); off += XP1;
    u16* wp5ah = (u16*)(W + off); off += WPA;
    u16* wp5al = (u16*)(W + off); off += WPA;
    u16* wp5ch = (u16*)(W + off); off += WPA;
    u16* wp5cl = (u16*)(W + off); off += WPA;
    u16* wp51h = (u16*)(W + off); off += WPB;
    u16* wp51l = (u16*)(W + off); off += WPB;
    u16* wp52h = (u16*)(W + off); off += WPB;
    u16* wp52l = (u16*)(W + off); off += WPB;
    float* c5a = (float*)(W + off); off += 1024;
    float* c5c = (float*)(W + off); off += 1024;
    float* c51 = (float*)(W + off); off += 1024;
    float* c52 = (float*)(W + off); off += 1024;
    float* b0  = (float*)(W + off); off += FT;   // feat1 fp32 NHWC
    float* b1  = (float*)(W + off); off += FT;   // feat2 fp32 NHWC
    float* b3a = (float*)(W + off); off += FT;   // sa_conv
    float* b3b = (float*)(W + off); off += FT;   // sc_conv
    // fallback q/v buffers alias b3a/b3b (live ranges disjoint)
    float* qbuf = b3a;
    float* vbuf = (float*)((char*)b3a + 1048576);

    // ---- prep
    border_zero<<<dim3(1040, 3), 256, 0, stream>>>(xp0h, xp0l, xp1h, xp1l, xp2h, xp2l);
    bn_prep_all<<<4, 128, 0, stream>>>(bn5a_s, bn5a_b, bn5a_m, bn5a_v,
                                       bn5c_s, bn5c_b, bn5c_m, bn5c_v,
                                       bn51_s, bn51_b, bn51_m, bn51_v,
                                       bn52_s, bn52_b, bn52_m, bn52_v,
                                       c5a, c5c, c51, c52);
    pack_w<512><<<dim3(2304, 1, 2), 256, 0, stream>>>(w5a, wp5ah, wp5al, w5c, wp5ch, wp5cl);
    pack_w<128><<<dim3(576, 1, 2), 256, 0, stream>>>(w51, wp51h, wp51l, w52, wp52h, wp52l);
    pack_x<<<dim3(8, 64, 4), 256, 0, stream>>>(x, xp0h, xp0l);

    // ---- feat1 = CBR(x,5a) [z=0], feat2 = CBR(x,5c) [z=1]; epilogue packs
    // the padded hi/lo inputs for conv51/conv52.
    conv_mfma<512, true><<<dim3(128, 1, 2), 256, 0, stream>>>(
        xp0h, xp0l, xp0h, xp0l,
        wp5ah, wp5al, wp5ch, wp5cl,
        c5a, c5c, b0, b1,
        xp1h, xp1l, xp2h, xp2l);

    // ---- guarded attention (no-ops when gamma == 0); overwrite staged inputs
    lin_q<<<64, 256, 0, stream>>>(g_sa, b0, q_w, q_b, qbuf);
    lin_v<<<256, 256, 0, stream>>>(g_sa, b0, v_w, v_b, vbuf);
    sa_attn<<<dim3(128, 4), 256, 0, stream>>>(g_sa, qbuf, vbuf, b0, xp1h, xp1l);
    ca_attn<<<dim3(128, 4), 128, 0, stream>>>(g_sc, b1, xp2h, xp2l);

    // ---- sa_conv = CBR(sa_feat,51) [z=0], sc_conv = CBR(sc_feat,52) [z=1]
    conv_mfma<128, false><<<dim3(128, 1, 2), 256, 0, stream>>>(
        xp1h, xp1l, xp2h, xp2l,
        wp51h, wp51l, wp52h, wp52l,
        c51, c52, b3a, b3b,
        nullptr, nullptr, nullptr, nullptr);

    // ---- out = 1x1(b3a + b3b) + bias, NCHW
    conv1x1<<<64, 256, 0, stream>>>(b3a, b3b, w8, b8, out);
}